// Round 4
// baseline (303.001 us; speedup 1.0000x reference)
//
#include <hip/hip_runtime.h>
#include <hip/hip_bf16.h>
#include <stdint.h>

// DiffLogic: 3-layer differentiable logic network.
// Round 4: MLP via fire-and-forget global_load_lds (no dest VGPR -> compiler
// cannot serialize it against uses). Per block: 32 x 1KB column DMAs into
// 32 KB LDS, one barrier, compute 16 gates from LDS, coalesced store.

#define BATCH   256
#define IN_DIM  1024
#define WIDTH   64000
#define NGROUP  10
#define GSIZE   6400      // WIDTH / NGROUP
#define TAU     30.0f
#define GPB     16        // gates per block; 32 columns = 32 KB LDS
#define COLS    (2*GPB)

// ---------------------------------------------------------------- transpose
// x:(256,1024) row-major -> xT:(1024,256)
__global__ __launch_bounds__(256) void transpose_kernel(
    const float* __restrict__ x, float* __restrict__ xT)
{
    __shared__ float tile[64][65];
    const int c0 = (blockIdx.x & 15) * 64;
    const int b0 = (blockIdx.x >> 4) * 64;
    const int lt = threadIdx.x & 63;
    const int wt = threadIdx.x >> 6;
    for (int r = wt; r < 64; r += 4)
        tile[r][lt] = x[(b0 + r) * IN_DIM + c0 + lt];
    __syncthreads();
    for (int r = wt; r < 64; r += 4)
        xT[(c0 + r) * BATCH + b0 + lt] = tile[lt][r];
}

// ---------------------------------------------------------------- coefficients
__global__ __launch_bounds__(256) void coef_kernel(
    const float* __restrict__ w1, const float* __restrict__ w2,
    const float* __restrict__ w3,
    float4* __restrict__ c1o, float4* __restrict__ c2o, float4* __restrict__ c3o)
{
    const int id = blockIdx.x * 256 + threadIdx.x;
    const int layer = id / WIDTH;
    const int j = id - layer * WIDTH;
    const float* w = (layer == 0) ? w1 : (layer == 1) ? w2 : w3;
    float4* cc     = (layer == 0) ? c1o : (layer == 1) ? c2o : c3o;

    const float4* w4 = (const float4*)(w + (size_t)j * 16);
    float4 q0 = w4[0], q1 = w4[1], q2 = w4[2], q3 = w4[3];
    float p[16] = {q0.x,q0.y,q0.z,q0.w, q1.x,q1.y,q1.z,q1.w,
                   q2.x,q2.y,q2.z,q2.w, q3.x,q3.y,q3.z,q3.w};
    float m = p[0];
    #pragma unroll
    for (int i = 1; i < 16; ++i) m = fmaxf(m, p[i]);
    float s = 0.f;
    #pragma unroll
    for (int i = 0; i < 16; ++i) { p[i] = __expf(p[i] - m); s += p[i]; }
    const float inv = 1.0f / s;

    float c0 = (p[8]+p[9]+p[10]+p[11]+p[12]+p[13]+p[14]+p[15]) * inv;
    float c1 = (p[2]+p[3]+p[6]+p[7] - p[8]-p[9]-p[12]-p[13]) * inv;
    float c2 = (p[4]+p[5]+p[6]+p[7] - p[8]-p[9]-p[10]-p[11]) * inv;
    float c3 = (p[1]-p[2]-p[4]-2.f*p[6]-p[7]+p[8]+2.f*p[9]+p[11]+p[13]-p[14]) * inv;
    cc[j] = make_float4(c0, c1, c2, c3);
}

// ---------------------------------------------------------------- logic layer
// in : (in_width, 64) float4 columns (width-major, batch contiguous)
// LDS: cols[c] = 1KB column; c<GPB -> A of gate c, else B of gate c-GPB.
template<bool FINAL>
__global__ __launch_bounds__(256) void logic_layer_kernel(
    const float4* __restrict__ in,
    const float4* __restrict__ coefs,
    const int*    __restrict__ ia,
    const int*    __restrict__ ib,
    float4*       __restrict__ out,
    float*        __restrict__ red_out)
{
    __shared__ float cols[COLS][BATCH];       // 32 KB
    const int lane = threadIdx.x & 63;
    const int wave = threadIdx.x >> 6;
    const int j0 = blockIdx.x * GPB;

    // Stage: each wave issues 8 fire-and-forget 1KB column DMAs.
    #pragma unroll
    for (int t = 0; t < COLS / 4; ++t) {
        const int c = wave * (COLS / 4) + t;                 // wave-uniform
        const int g = c & (GPB - 1);
        const int src = (c < GPB) ? ia[j0 + g] : ib[j0 + g]; // scalar load
        const float4* gp = in + (size_t)src * 64 + lane;     // per-lane addr
        __builtin_amdgcn_global_load_lds(
            (const __attribute__((address_space(1))) uint32_t*)gp,
            (__attribute__((address_space(3))) uint32_t*)&cols[c][0],
            16, 0, 0);
    }
    __syncthreads();   // drains vmcnt -> all 32 columns resident

    // Compute: wave w handles gates w*4 .. w*4+3 from LDS.
    float4 acc = make_float4(0.f, 0.f, 0.f, 0.f);
    #pragma unroll
    for (int u = 0; u < GPB / 4; ++u) {
        const int g = wave * (GPB / 4) + u;
        const float4 c = coefs[j0 + g];
        const float4 A = ((const float4*)&cols[g][0])[lane];
        const float4 B = ((const float4*)&cols[GPB + g][0])[lane];
        float4 r;
        r.x = fmaf(c.w, A.x * B.x, fmaf(c.z, B.x, fmaf(c.y, A.x, c.x)));
        r.y = fmaf(c.w, A.y * B.y, fmaf(c.z, B.y, fmaf(c.y, A.y, c.x)));
        r.z = fmaf(c.w, A.z * B.z, fmaf(c.z, B.z, fmaf(c.y, A.z, c.x)));
        r.w = fmaf(c.w, A.w * B.w, fmaf(c.z, B.w, fmaf(c.y, A.w, c.x)));
        if (FINAL) {
            acc.x += r.x; acc.y += r.y; acc.z += r.z; acc.w += r.w;
        } else {
            out[(size_t)(j0 + g) * 64 + lane] = r;
        }
    }

    if (FINAL) {
        __syncthreads();                       // columns no longer needed
        float4* s = (float4*)&cols[0][0];      // reuse LDS for reduction
        s[wave * 64 + lane] = acc;
        __syncthreads();
        if (wave == 0) {
            float4 t0 = s[0*64+lane], t1 = s[1*64+lane],
                   t2 = s[2*64+lane], t3 = s[3*64+lane];
            const float sc = 1.0f / TAU;
            const int grp = (blockIdx.x * GPB) / GSIZE;   // block within one group
            const int b0 = lane * 4;
            atomicAdd(&red_out[(b0 + 0) * NGROUP + grp], (t0.x + t1.x + t2.x + t3.x) * sc);
            atomicAdd(&red_out[(b0 + 1) * NGROUP + grp], (t0.y + t1.y + t2.y + t3.y) * sc);
            atomicAdd(&red_out[(b0 + 2) * NGROUP + grp], (t0.z + t1.z + t2.z + t3.z) * sc);
            atomicAdd(&red_out[(b0 + 3) * NGROUP + grp], (t0.w + t1.w + t2.w + t3.w) * sc);
        }
    }
}

// ---------------------------------------------------------------- launch
extern "C" void kernel_launch(void* const* d_in, const int* in_sizes, int n_in,
                              void* d_out, int out_size, void* d_ws, size_t ws_size,
                              hipStream_t stream)
{
    const float* x   = (const float*)d_in[0];
    const float* w1  = (const float*)d_in[1];
    const float* w2  = (const float*)d_in[2];
    const float* w3  = (const float*)d_in[3];
    const int*   ia1 = (const int*)d_in[4];
    const int*   ib1 = (const int*)d_in[5];
    const int*   ia2 = (const int*)d_in[6];
    const int*   ib2 = (const int*)d_in[7];
    const int*   ia3 = (const int*)d_in[8];
    const int*   ib3 = (const int*)d_in[9];
    float* out = (float*)d_out;

    // workspace layout (floats): xT | h1 | h2 | c1 | c2 | c3  ~= 135 MB
    float* ws = (float*)d_ws;
    float* xT = ws;
    float* h1 = xT + (size_t)IN_DIM * BATCH;
    float* h2 = h1 + (size_t)WIDTH * BATCH;
    float* c1 = h2 + (size_t)WIDTH * BATCH;
    float* c2 = c1 + (size_t)WIDTH * 4;
    float* c3 = c2 + (size_t)WIDTH * 4;

    hipMemsetAsync(d_out, 0, (size_t)out_size * sizeof(float), stream);

    transpose_kernel<<<64, 256, 0, stream>>>(x, xT);
    coef_kernel<<<(3 * WIDTH) / 256, 256, 0, stream>>>(w1, w2, w3,
                                                       (float4*)c1, (float4*)c2, (float4*)c3);

    logic_layer_kernel<false><<<WIDTH / GPB, 256, 0, stream>>>(
        (const float4*)xT, (const float4*)c1, ia1, ib1, (float4*)h1, nullptr);
    logic_layer_kernel<false><<<WIDTH / GPB, 256, 0, stream>>>(
        (const float4*)h1, (const float4*)c2, ia2, ib2, (float4*)h2, nullptr);
    logic_layer_kernel<true><<<WIDTH / GPB, 256, 0, stream>>>(
        (const float4*)h2, (const float4*)c3, ia3, ib3, nullptr, out);
}

// Round 5
// 161.322 us; speedup vs baseline: 1.8782x; 1.8782x over previous
//
#include <hip/hip_runtime.h>
#include <hip/hip_bf16.h>

// DiffLogic: 3-layer differentiable logic network.
// Round 5: occupancy attack. 500 blocks x 1024 threads (16 waves), 128
// gates/block, 8 serial gates per wave, plain float4 gathers (codegen the
// compiler handles well). 2 blocks/CU x 16 waves = 32 resident waves/CU,
// each with ~2 gathers in flight -> ~64 outstanding 1KB reads per CU.

#define BATCH   256
#define IN_DIM  1024
#define WIDTH   64000
#define NGROUP  10
#define GSIZE   6400      // WIDTH / NGROUP
#define TAU     30.0f
#define NWAVE   16        // waves per block
#define GPW     8         // serial gates per wave
#define GPB     (NWAVE*GPW)   // 128 gates/block; 6400 % 128 == 0
#define NBLK    (WIDTH/GPB)   // 500

// ---------------------------------------------------------------- transpose
// x:(256,1024) row-major -> xT:(1024,256)
__global__ __launch_bounds__(256) void transpose_kernel(
    const float* __restrict__ x, float* __restrict__ xT)
{
    __shared__ float tile[64][65];
    const int c0 = (blockIdx.x & 15) * 64;
    const int b0 = (blockIdx.x >> 4) * 64;
    const int lt = threadIdx.x & 63;
    const int wt = threadIdx.x >> 6;
    for (int r = wt; r < 64; r += 4)
        tile[r][lt] = x[(b0 + r) * IN_DIM + c0 + lt];
    __syncthreads();
    for (int r = wt; r < 64; r += 4)
        xT[(c0 + r) * BATCH + b0 + lt] = tile[lt][r];
}

// ---------------------------------------------------------------- coefficients
__global__ __launch_bounds__(256) void coef_kernel(
    const float* __restrict__ w1, const float* __restrict__ w2,
    const float* __restrict__ w3,
    float4* __restrict__ c1o, float4* __restrict__ c2o, float4* __restrict__ c3o)
{
    const int id = blockIdx.x * 256 + threadIdx.x;
    const int layer = id / WIDTH;
    const int j = id - layer * WIDTH;
    const float* w = (layer == 0) ? w1 : (layer == 1) ? w2 : w3;
    float4* cc     = (layer == 0) ? c1o : (layer == 1) ? c2o : c3o;

    const float4* w4 = (const float4*)(w + (size_t)j * 16);
    float4 q0 = w4[0], q1 = w4[1], q2 = w4[2], q3 = w4[3];
    float p[16] = {q0.x,q0.y,q0.z,q0.w, q1.x,q1.y,q1.z,q1.w,
                   q2.x,q2.y,q2.z,q2.w, q3.x,q3.y,q3.z,q3.w};
    float m = p[0];
    #pragma unroll
    for (int i = 1; i < 16; ++i) m = fmaxf(m, p[i]);
    float s = 0.f;
    #pragma unroll
    for (int i = 0; i < 16; ++i) { p[i] = __expf(p[i] - m); s += p[i]; }
    const float inv = 1.0f / s;

    float c0 = (p[8]+p[9]+p[10]+p[11]+p[12]+p[13]+p[14]+p[15]) * inv;
    float c1 = (p[2]+p[3]+p[6]+p[7] - p[8]-p[9]-p[12]-p[13]) * inv;
    float c2 = (p[4]+p[5]+p[6]+p[7] - p[8]-p[9]-p[10]-p[11]) * inv;
    float c3 = (p[1]-p[2]-p[4]-2.f*p[6]-p[7]+p[8]+2.f*p[9]+p[11]+p[13]-p[14]) * inv;
    cc[j] = make_float4(c0, c1, c2, c3);
}

// ---------------------------------------------------------------- logic layer
// in : (in_width, 64) float4 columns (width-major, batch contiguous)
template<bool FINAL>
__global__ __launch_bounds__(1024) void logic_layer_kernel(
    const float4* __restrict__ in,
    const float4* __restrict__ coefs,
    const int*    __restrict__ ia,
    const int*    __restrict__ ib,
    float4*       __restrict__ out,
    float*        __restrict__ red_out)
{
    const int lane = threadIdx.x & 63;
    const int wave = __builtin_amdgcn_readfirstlane(threadIdx.x >> 6);
    const int jw = blockIdx.x * GPB + wave * GPW;   // wave's 8 contiguous gates

    // Metadata upfront (wave-uniform -> scalar, contiguous 32B runs).
    int av[GPW], bv[GPW];
    #pragma unroll
    for (int u = 0; u < GPW; ++u) { av[u] = ia[jw + u]; bv[u] = ib[jw + u]; }

    float4 acc = make_float4(0.f, 0.f, 0.f, 0.f);

    #pragma unroll
    for (int u = 0; u < GPW; ++u) {
        const float4 c = coefs[jw + u];
        const float4 A = in[(size_t)av[u] * 64 + lane];
        const float4 B = in[(size_t)bv[u] * 64 + lane];
        float4 r;
        r.x = fmaf(c.w, A.x * B.x, fmaf(c.z, B.x, fmaf(c.y, A.x, c.x)));
        r.y = fmaf(c.w, A.y * B.y, fmaf(c.z, B.y, fmaf(c.y, A.y, c.x)));
        r.z = fmaf(c.w, A.z * B.z, fmaf(c.z, B.z, fmaf(c.y, A.z, c.x)));
        r.w = fmaf(c.w, A.w * B.w, fmaf(c.z, B.w, fmaf(c.y, A.w, c.x)));
        if (FINAL) {
            acc.x += r.x; acc.y += r.y; acc.z += r.z; acc.w += r.w;
        } else {
            out[(size_t)(jw + u) * 64 + lane] = r;
        }
    }

    if (FINAL) {
        __shared__ float4 s[NWAVE][64];     // 16 KB
        s[wave][lane] = acc;
        __syncthreads();
        if (wave == 0) {
            float4 t = s[0][lane];
            #pragma unroll
            for (int w = 1; w < NWAVE; ++w) {
                float4 q = s[w][lane];
                t.x += q.x; t.y += q.y; t.z += q.z; t.w += q.w;
            }
            const float sc = 1.0f / TAU;
            const int grp = (blockIdx.x * GPB) / GSIZE;   // block within one group
            const int b0 = lane * 4;
            atomicAdd(&red_out[(b0 + 0) * NGROUP + grp], t.x * sc);
            atomicAdd(&red_out[(b0 + 1) * NGROUP + grp], t.y * sc);
            atomicAdd(&red_out[(b0 + 2) * NGROUP + grp], t.z * sc);
            atomicAdd(&red_out[(b0 + 3) * NGROUP + grp], t.w * sc);
        }
    }
}

// ---------------------------------------------------------------- launch
extern "C" void kernel_launch(void* const* d_in, const int* in_sizes, int n_in,
                              void* d_out, int out_size, void* d_ws, size_t ws_size,
                              hipStream_t stream)
{
    const float* x   = (const float*)d_in[0];
    const float* w1  = (const float*)d_in[1];
    const float* w2  = (const float*)d_in[2];
    const float* w3  = (const float*)d_in[3];
    const int*   ia1 = (const int*)d_in[4];
    const int*   ib1 = (const int*)d_in[5];
    const int*   ia2 = (const int*)d_in[6];
    const int*   ib2 = (const int*)d_in[7];
    const int*   ia3 = (const int*)d_in[8];
    const int*   ib3 = (const int*)d_in[9];
    float* out = (float*)d_out;

    // workspace layout (floats): xT | h1 | h2 | c1 | c2 | c3  ~= 135 MB
    float* ws = (float*)d_ws;
    float* xT = ws;
    float* h1 = xT + (size_t)IN_DIM * BATCH;
    float* h2 = h1 + (size_t)WIDTH * BATCH;
    float* c1 = h2 + (size_t)WIDTH * BATCH;
    float* c2 = c1 + (size_t)WIDTH * 4;
    float* c3 = c2 + (size_t)WIDTH * 4;

    hipMemsetAsync(d_out, 0, (size_t)out_size * sizeof(float), stream);

    transpose_kernel<<<64, 256, 0, stream>>>(x, xT);
    coef_kernel<<<(3 * WIDTH) / 256, 256, 0, stream>>>(w1, w2, w3,
                                                       (float4*)c1, (float4*)c2, (float4*)c3);

    logic_layer_kernel<false><<<NBLK, 1024, 0, stream>>>(
        (const float4*)xT, (const float4*)c1, ia1, ib1, (float4*)h1, nullptr);
    logic_layer_kernel<false><<<NBLK, 1024, 0, stream>>>(
        (const float4*)h1, (const float4*)c2, ia2, ib2, (float4*)h2, nullptr);
    logic_layer_kernel<true><<<NBLK, 1024, 0, stream>>>(
        (const float4*)h2, (const float4*)c3, ia3, ib3, nullptr, out);
}

// Round 6
// 143.545 us; speedup vs baseline: 2.1108x; 1.1238x over previous
//
#include <hip/hip_runtime.h>
#include <hip/hip_bf16.h>
#include <stdint.h>

// DiffLogic: 3-layer differentiable logic network.
// Round 6: keep R5's 32-waves/CU structure (500 blocks x 1024 threads, the
// proven win), store activations as bf16 -> halves gather + write traffic.
// Compute stays fp32 in registers; output threshold (2.14) has ~200x slack.

#define BATCH   256
#define IN_DIM  1024
#define WIDTH   64000
#define NGROUP  10
#define GSIZE   6400      // WIDTH / NGROUP
#define TAU     30.0f
#define NWAVE   16        // waves per block
#define GPW     8         // serial gates per wave
#define GPB     (NWAVE*GPW)   // 128 gates/block; 6400 % 128 == 0
#define NBLK    (WIDTH/GPB)   // 500

typedef unsigned short ushort_t;

static __device__ __forceinline__ float bf2f(ushort_t s) {
    return __uint_as_float((uint32_t)s << 16);
}
static __device__ __forceinline__ ushort_t f2bf(float f) {   // RNE
    uint32_t u = __float_as_uint(f);
    return (ushort_t)((u + 0x7fffu + ((u >> 16) & 1u)) >> 16);
}

// ---------------------------------------------------------------- transpose
// x:(256,1024) f32 row-major -> xT:(1024,256) bf16
__global__ __launch_bounds__(256) void transpose_kernel(
    const float* __restrict__ x, ushort_t* __restrict__ xT)
{
    __shared__ float tile[64][65];
    const int c0 = (blockIdx.x & 15) * 64;
    const int b0 = (blockIdx.x >> 4) * 64;
    const int lt = threadIdx.x & 63;
    const int wt = threadIdx.x >> 6;
    for (int r = wt; r < 64; r += 4)
        tile[r][lt] = x[(b0 + r) * IN_DIM + c0 + lt];
    __syncthreads();
    for (int r = wt; r < 64; r += 4)
        xT[(c0 + r) * BATCH + b0 + lt] = f2bf(tile[lt][r]);
}

// ---------------------------------------------------------------- coefficients
__global__ __launch_bounds__(256) void coef_kernel(
    const float* __restrict__ w1, const float* __restrict__ w2,
    const float* __restrict__ w3,
    float4* __restrict__ c1o, float4* __restrict__ c2o, float4* __restrict__ c3o)
{
    const int id = blockIdx.x * 256 + threadIdx.x;
    const int layer = id / WIDTH;
    const int j = id - layer * WIDTH;
    const float* w = (layer == 0) ? w1 : (layer == 1) ? w2 : w3;
    float4* cc     = (layer == 0) ? c1o : (layer == 1) ? c2o : c3o;

    const float4* w4 = (const float4*)(w + (size_t)j * 16);
    float4 q0 = w4[0], q1 = w4[1], q2 = w4[2], q3 = w4[3];
    float p[16] = {q0.x,q0.y,q0.z,q0.w, q1.x,q1.y,q1.z,q1.w,
                   q2.x,q2.y,q2.z,q2.w, q3.x,q3.y,q3.z,q3.w};
    float m = p[0];
    #pragma unroll
    for (int i = 1; i < 16; ++i) m = fmaxf(m, p[i]);
    float s = 0.f;
    #pragma unroll
    for (int i = 0; i < 16; ++i) { p[i] = __expf(p[i] - m); s += p[i]; }
    const float inv = 1.0f / s;

    float c0 = (p[8]+p[9]+p[10]+p[11]+p[12]+p[13]+p[14]+p[15]) * inv;
    float c1 = (p[2]+p[3]+p[6]+p[7] - p[8]-p[9]-p[12]-p[13]) * inv;
    float c2 = (p[4]+p[5]+p[6]+p[7] - p[8]-p[9]-p[10]-p[11]) * inv;
    float c3 = (p[1]-p[2]-p[4]-2.f*p[6]-p[7]+p[8]+2.f*p[9]+p[11]+p[13]-p[14]) * inv;
    cc[j] = make_float4(c0, c1, c2, c3);
}

// ---------------------------------------------------------------- logic layer
// in : (in_width, 256) bf16 columns (width-major, batch contiguous)
// gather = 512 B/column, ushort4 (8 B) per lane, fully coalesced.
template<bool FINAL>
__global__ __launch_bounds__(1024) void logic_layer_kernel(
    const ushort_t* __restrict__ in,
    const float4*   __restrict__ coefs,
    const int*      __restrict__ ia,
    const int*      __restrict__ ib,
    ushort_t*       __restrict__ out,
    float*          __restrict__ red_out)
{
    const int lane = threadIdx.x & 63;
    const int wave = __builtin_amdgcn_readfirstlane(threadIdx.x >> 6);
    const int jw = blockIdx.x * GPB + wave * GPW;   // wave's 8 contiguous gates

    int av[GPW], bv[GPW];
    #pragma unroll
    for (int u = 0; u < GPW; ++u) { av[u] = ia[jw + u]; bv[u] = ib[jw + u]; }

    float4 acc = make_float4(0.f, 0.f, 0.f, 0.f);

    #pragma unroll
    for (int u = 0; u < GPW; ++u) {
        const float4 c = coefs[jw + u];
        const ushort4 a4 = ((const ushort4*)(in + (size_t)av[u] * BATCH))[lane];
        const ushort4 b4 = ((const ushort4*)(in + (size_t)bv[u] * BATCH))[lane];
        const float Ax = bf2f(a4.x), Ay = bf2f(a4.y), Az = bf2f(a4.z), Aw = bf2f(a4.w);
        const float Bx = bf2f(b4.x), By = bf2f(b4.y), Bz = bf2f(b4.z), Bw = bf2f(b4.w);
        float4 r;
        r.x = fmaf(c.w, Ax * Bx, fmaf(c.z, Bx, fmaf(c.y, Ax, c.x)));
        r.y = fmaf(c.w, Ay * By, fmaf(c.z, By, fmaf(c.y, Ay, c.x)));
        r.z = fmaf(c.w, Az * Bz, fmaf(c.z, Bz, fmaf(c.y, Az, c.x)));
        r.w = fmaf(c.w, Aw * Bw, fmaf(c.z, Bw, fmaf(c.y, Aw, c.x)));
        if (FINAL) {
            acc.x += r.x; acc.y += r.y; acc.z += r.z; acc.w += r.w;
        } else {
            ushort4 o;
            o.x = f2bf(r.x); o.y = f2bf(r.y); o.z = f2bf(r.z); o.w = f2bf(r.w);
            ((ushort4*)(out + (size_t)(jw + u) * BATCH))[lane] = o;
        }
    }

    if (FINAL) {
        __shared__ float4 s[NWAVE][64];     // 16 KB
        s[wave][lane] = acc;
        __syncthreads();
        if (wave == 0) {
            float4 t = s[0][lane];
            #pragma unroll
            for (int w = 1; w < NWAVE; ++w) {
                float4 q = s[w][lane];
                t.x += q.x; t.y += q.y; t.z += q.z; t.w += q.w;
            }
            const float sc = 1.0f / TAU;
            const int grp = (blockIdx.x * GPB) / GSIZE;   // block within one group
            const int b0 = lane * 4;
            atomicAdd(&red_out[(b0 + 0) * NGROUP + grp], t.x * sc);
            atomicAdd(&red_out[(b0 + 1) * NGROUP + grp], t.y * sc);
            atomicAdd(&red_out[(b0 + 2) * NGROUP + grp], t.z * sc);
            atomicAdd(&red_out[(b0 + 3) * NGROUP + grp], t.w * sc);
        }
    }
}

// ---------------------------------------------------------------- launch
extern "C" void kernel_launch(void* const* d_in, const int* in_sizes, int n_in,
                              void* d_out, int out_size, void* d_ws, size_t ws_size,
                              hipStream_t stream)
{
    const float* x   = (const float*)d_in[0];
    const float* w1  = (const float*)d_in[1];
    const float* w2  = (const float*)d_in[2];
    const float* w3  = (const float*)d_in[3];
    const int*   ia1 = (const int*)d_in[4];
    const int*   ib1 = (const int*)d_in[5];
    const int*   ia2 = (const int*)d_in[6];
    const int*   ib2 = (const int*)d_in[7];
    const int*   ia3 = (const int*)d_in[8];
    const int*   ib3 = (const int*)d_in[9];
    float* out = (float*)d_out;

    // workspace (byte offsets, 16B-aligned): xT | h1 | h2 | c1 | c2 | c3 ~= 69 MB
    char* ws = (char*)d_ws;
    ushort_t* xT = (ushort_t*)ws;                                   // 0.5 MB
    ushort_t* h1 = (ushort_t*)(ws + ((size_t)IN_DIM * BATCH * 2));  // 32.77 MB
    ushort_t* h2 = h1 + (size_t)WIDTH * BATCH;
    float*    c1 = (float*)(h2 + (size_t)WIDTH * BATCH);
    float*    c2 = c1 + (size_t)WIDTH * 4;
    float*    c3 = c2 + (size_t)WIDTH * 4;

    hipMemsetAsync(d_out, 0, (size_t)out_size * sizeof(float), stream);

    transpose_kernel<<<64, 256, 0, stream>>>(x, xT);
    coef_kernel<<<(3 * WIDTH) / 256, 256, 0, stream>>>(w1, w2, w3,
                                                       (float4*)c1, (float4*)c2, (float4*)c3);

    logic_layer_kernel<false><<<NBLK, 1024, 0, stream>>>(
        xT, (const float4*)c1, ia1, ib1, h1, nullptr);
    logic_layer_kernel<false><<<NBLK, 1024, 0, stream>>>(
        h1, (const float4*)c2, ia2, ib2, h2, nullptr);
    logic_layer_kernel<true><<<NBLK, 1024, 0, stream>>>(
        h2, (const float4*)c3, ia3, ib3, nullptr, out);
}